// Round 17
// baseline (601.088 us; speedup 1.0000x reference)
//
#include <hip/hip_runtime.h>

// Mixed2DEpsNetwork: G=2000 graphs x 16 nodes, H=128, 6 EGNN layers + edge MLP.
// R17: h and agg live in LDS as bf16 hi/lo SHADOW PAIRS ONLY (no fp32 master):
// GEMM A-frags are direct ds_read_b128 (zero split VALU in hot loops, shorter
// dep chain), splits happen only at producer sites (init, agg write, residual
// reconstruct hi+lo -> add -> re-split). LDS stays ~34KB -> 4 blocks/CU kept.
// R16 proved accv-across-GEMM is free and that the spill came from the
// in-loop split temps (~24 regs) -- now deleted. bf16x3 MFMA, (256,4).

#define G_GRAPHS 2000
#define NPG 16
#define HID 128
#define FDIM 28
#define NLAYER 6
#define NNODES 32000
#define EL_PER_G 32
#define EG_PER_G 240
#define EL_TOT (G_GRAPHS*EL_PER_G)
#define EG_TOT (G_GRAPHS*EG_PER_G)
#define TMAX 32

// fp32 LDS [16][128] with per-row XOR swizzle (8-elem granule)
#define MC(r_, c_) ((r_)*HID + ((c_) ^ (((r_) & 7) << 3)))

typedef __attribute__((ext_vector_type(8))) short bf16x8;
typedef __attribute__((ext_vector_type(4))) float f32x4;

__device__ __forceinline__ float silu_f(float x) {
    return x * __builtin_amdgcn_rcpf(1.0f + __expf(-x));
}
__device__ __forceinline__ int clampT(int t) {
    return t < 0 ? 0 : (t > TMAX-1 ? TMAX-1 : t);
}
__device__ __forceinline__ unsigned short bf16_rne(float x) {
    unsigned u = __float_as_uint(x);
    return (unsigned short)((u + 0x7FFFu + ((u >> 16) & 1u)) >> 16);
}
__device__ __forceinline__ void split2(float x, unsigned short &hi, unsigned short &lo) {
    hi = bf16_rne(x);
    float fh = __uint_as_float((unsigned)hi << 16);
    lo = bf16_rne(x - fh);
}
__device__ __forceinline__ float bf16_to_f(short s) {
    return __uint_as_float((unsigned)(unsigned short)s << 16);
}

// kt-outer GEMM over K=128, NT contiguous ct-tiles. A-frags read DIRECTLY as
// bf16x8 from hi/lo short LDS buffers (swizzled) -- no conversion VALU.
// Incremental B pointers + unroll 1. Per-acc chain: kt asc; hh,hl,lh.
template<int NT>
__device__ __forceinline__ void mm_nt_s16(const short* __restrict__ ahbuf,
                                          const short* __restrict__ albuf,
                                          const unsigned short* __restrict__ Bh,
                                          const unsigned short* __restrict__ Bl,
                                          int ctbase, int lane, f32x4* acc) {
    const int n = lane & 15, kq = lane >> 4;
    const int sw = (n & 7) << 3;
    const short* aph = ahbuf + n*HID;
    const short* apl = albuf + n*HID;
    const unsigned short* bh = Bh + ((size_t)(ctbase*4)*64 + lane)*8;
    const unsigned short* bl = Bl + ((size_t)(ctbase*4)*64 + lane)*8;
    #pragma unroll 1
    for (int kt = 0; kt < 4; kt++) {
        int idx = (kt*32 + kq*8) ^ sw;
        bf16x8 ah = *(const bf16x8*)(aph + idx);
        bf16x8 al = *(const bf16x8*)(apl + idx);
        const unsigned short* ph = bh;
        const unsigned short* pl = bl;
        #pragma unroll
        for (int t = 0; t < NT; t++) {
            bf16x8 vh = *(const bf16x8*)ph;
            bf16x8 vl = *(const bf16x8*)pl;
            acc[t] = __builtin_amdgcn_mfma_f32_16x16x32_bf16(ah, vh, acc[t], 0, 0, 0);
            acc[t] = __builtin_amdgcn_mfma_f32_16x16x32_bf16(ah, vl, acc[t], 0, 0, 0);
            acc[t] = __builtin_amdgcn_mfma_f32_16x16x32_bf16(al, vh, acc[t], 0, 0, 0);
            ph += 2048;   // next ct-tile (4 kt * 64 lanes * 8)
            pl += 2048;
        }
        bh += 512;        // next kt (64 lanes * 8)
        bl += 512;
    }
}

// One 16x16 tile, A from bf16-short swizzled buffer (MLP path), incremental ptrs.
__device__ __forceinline__ f32x4 mm_ct_s16(const short* __restrict__ ahbuf,
                                           const short* __restrict__ albuf,
                                           const unsigned short* __restrict__ Bh,
                                           const unsigned short* __restrict__ Bl,
                                           int ct, int lane, f32x4 acc) {
    const int n = lane & 15, kq = lane >> 4;
    const unsigned short* bh = Bh + ((size_t)(ct*4)*64 + lane)*8;
    const unsigned short* bl = Bl + ((size_t)(ct*4)*64 + lane)*8;
    #pragma unroll 1
    for (int kt = 0; kt < 4; kt++) {
        int sidx = (n*HID + kt*32 + kq*8) ^ ((n & 7) << 3);
        bf16x8 ah = *(const bf16x8*)(ahbuf + sidx);
        bf16x8 al = *(const bf16x8*)(albuf + sidx);
        bf16x8 vh = *(const bf16x8*)bh;
        bf16x8 vl = *(const bf16x8*)bl;
        acc = __builtin_amdgcn_mfma_f32_16x16x32_bf16(ah, vh, acc, 0, 0, 0);
        acc = __builtin_amdgcn_mfma_f32_16x16x32_bf16(ah, vl, acc, 0, 0, 0);
        acc = __builtin_amdgcn_mfma_f32_16x16x32_bf16(al, vh, acc, 0, 0, 0);
        bh += 512;
        bl += 512;
    }
    return acc;
}

// split 8 fp32 -> bf16 hi/lo fragments (producer sites only)
__device__ __forceinline__ void split8(const float* vv, bf16x8& h8, bf16x8& l8) {
    union { unsigned short s[8]; bf16x8 v; } H, L;
    #pragma unroll
    for (int i = 0; i < 8; i++) split2(vv[i], H.s[i], L.s[i]);
    h8 = H.v; l8 = L.v;
}

// Pack weights into MFMA B-fragment order, bf16 hi/lo.
// blocks 0..35: encoder (layer l = b/6, mat m = b%6: Wg0,Wg1,Wl0,Wl1,Wn0,Wn1)
// block 36: W00 (W0 rows 0..127); block 37: W1 (128x64).
__global__ void __launch_bounds__(256) k_pack(
    const float* __restrict__ Wg, const float* __restrict__ Wl,
    const float* __restrict__ Wn, const float* __restrict__ W0,
    const float* __restrict__ W1,
    unsigned short* __restrict__ encPh, unsigned short* __restrict__ encPl,
    unsigned short* __restrict__ w0Ph, unsigned short* __restrict__ w0Pl,
    unsigned short* __restrict__ w1Ph, unsigned short* __restrict__ w1Pl)
{
    int b = blockIdx.x, t = threadIdx.x;
    const float* src; int ldN, elems; unsigned short *dh, *dl;
    if (b < 36) {
        int l = b / 6, m = b % 6;
        src = (m == 0) ? Wg + (size_t)l*257*HID
            : (m == 1) ? Wg + (size_t)l*257*HID + 128*HID
            : (m == 2) ? Wl + (size_t)l*512*HID
            : (m == 3) ? Wl + (size_t)l*512*HID + 128*HID
            : (m == 4) ? Wn + (size_t)l*256*HID
            :            Wn + (size_t)l*256*HID + 128*HID;
        ldN = HID; elems = 16384;
        dh = encPh + (size_t)b*16384; dl = encPl + (size_t)b*16384;
    } else if (b == 36) {
        src = W0; ldN = HID; elems = 16384; dh = w0Ph; dl = w0Pl;
    } else {
        src = W1; ldN = 64; elems = 8192; dh = w1Ph; dl = w1Pl;
    }
    for (int idx = t; idx < elems; idx += 256) {
        int j = idx & 7, lane = (idx >> 3) & 63, kt = (idx >> 9) & 3, ct = idx >> 11;
        int k = kt*32 + (lane >> 4)*8 + j;
        int n = ct*16 + (lane & 15);
        unsigned short hi, lo;
        split2(src[(size_t)k*ldN + n], hi, lo);
        dh[idx] = hi; dl[idx] = lo;
    }
}

// bondA[l][t][c] = bond_emb[t] @ Wl[l,256:384] + bl[l];  bondB: rows 384:512.
__global__ void __launch_bounds__(HID) k_tab_bond(
    const float* __restrict__ bond_emb, const float* __restrict__ Wl,
    const float* __restrict__ bl, float* __restrict__ bondA, float* __restrict__ bondB)
{
    int l = blockIdx.x >> 5, t = blockIdx.x & 31, c = threadIdx.x;
    const float* WlL = Wl + (size_t)l*512*HID;
    float accA = bl[l*HID + c], accB = 0.f;
    #pragma unroll 4
    for (int k = 0; k < HID; k++) {
        float e = bond_emb[t*HID + k];
        accA = fmaf(e, WlL[(256+k)*HID + c], accA);
        accB = fmaf(e, WlL[(384+k)*HID + c], accB);
    }
    bondA[(l*TMAX + t)*HID + c] = accA;
    bondB[(l*TMAX + t)*HID + c] = accB;
}

// pairT[tr][tp][c] = (bond_emb[tr]*bond_emb[tp]) @ W0[128:256] + b0
__global__ void __launch_bounds__(HID) k_tab_pair(
    const float* __restrict__ bond_emb, const float* __restrict__ W0,
    const float* __restrict__ b0, float* __restrict__ pairT)
{
    int tr = blockIdx.x >> 5, tp = blockIdx.x & 31, c = threadIdx.x;
    float acc = b0[c];
    #pragma unroll 4
    for (int k = 0; k < HID; k++)
        acc = fmaf(bond_emb[tr*HID + k] * bond_emb[tp*HID + k], W0[(HID+k)*HID + c], acc);
    pairT[(size_t)blockIdx.x*HID + c] = acc;
}

// h[n] = concat(atom_emb[at] + r@W, (p-r)@W)
__global__ void __launch_bounds__(256) k_init_h(
    const int* __restrict__ atom_type, const float* __restrict__ r_feat,
    const float* __restrict__ p_feat, const float* __restrict__ atom_emb,
    const float* __restrict__ afW, float* __restrict__ h)
{
    int n = blockIdx.x*4 + (threadIdx.x >> 6);
    int j = threadIdx.x & 63;
    int at = atom_type[n];
    float accr = 0.f, accp = 0.f;
    #pragma unroll
    for (int k = 0; k < FDIM; k++) {
        float w = afW[k*64 + j];
        accr = fmaf(r_feat[n*FDIM + k], w, accr);
        accp = fmaf(p_feat[n*FDIM + k], w, accp);
    }
    h[n*HID + j]      = atom_emb[at*64 + j] + accr;
    h[n*HID + 64 + j] = accp - accr;
}

// One block per graph; all 6 layers fused. LDS ~34KB (4 blocks/CU), (256,4).
__global__ void __launch_bounds__(256, 4) k_encoder(
    const float* __restrict__ pos,
    const int* __restrict__ eil, const int* __restrict__ etr, const int* __restrict__ etp,
    const int* __restrict__ eig,
    const float* __restrict__ Wg, const float* __restrict__ bg,
    const float* __restrict__ bn,
    const float* __restrict__ bondA, const float* __restrict__ bondB,
    const unsigned short* __restrict__ encPh, const unsigned short* __restrict__ encPl,
    float* __restrict__ h)
{
    __shared__ __align__(16) short h_hi[NPG*HID], h_lo[NPG*HID];  // 8KB: h shadows
    __shared__ __align__(16) float M0[NPG*HID], M1[NPG*HID];      // 16KB: A/Al, B/Bl
    __shared__ __align__(16) short g_hi[NPG*HID], g_lo[NPG*HID];  // 8KB: agg shadows
    __shared__ float d2m[NPG][NPG];
    __shared__ unsigned msk[NPG];
    __shared__ float px[NPG], py[NPG], pz[NPG];
    __shared__ int llist[NPG][2];
    __shared__ int lcnt[NPG];
    __shared__ int lsrc_s[EL_PER_G], ltr_s[EL_PER_G], ltp_s[EL_PER_G];

    const int g = blockIdx.x;
    const int tid = threadIdx.x;
    const int lane = tid & 63;
    const int w    = tid >> 6;     // wave id 0..3
    const int c    = tid & 127;    // phase-2 column
    const int dh2  = tid >> 7;     // phase-2 dest half

    // ---- load h, split to hi/lo shadows (swizzled); topology
    for (int idx = tid; idx < NPG*HID; idx += 256) {
        int n = idx >> 7, cc = idx & 127;
        float v = h[(size_t)g*NPG*HID + idx];
        unsigned short hi, lo;
        split2(v, hi, lo);
        int s = MC(n, cc);
        h_hi[s] = (short)hi;
        h_lo[s] = (short)lo;
    }
    if (tid < NPG) {
        px[tid] = pos[(g*NPG + tid)*3 + 0];
        py[tid] = pos[(g*NPG + tid)*3 + 1];
        pz[tid] = pos[(g*NPG + tid)*3 + 2];
        lcnt[tid] = 0; msk[tid] = 0u;
    }
    __syncthreads();
    if (tid < EG_PER_G) {
        int e = g*EG_PER_G + tid;
        int s = eig[e] - g*NPG;
        int d = eig[EG_TOT + e] - g*NPG;
        float dx = px[s]-px[d], dy = py[s]-py[d], dz = pz[s]-pz[d];
        d2m[d][s] = dx*dx + dy*dy + dz*dz;
        atomicOr(&msk[d], 1u << s);
    }
    if (tid < EL_PER_G) {
        int e = g*EL_PER_G + tid;
        int s = eil[e] - g*NPG;
        int d = eil[EL_TOT + e] - g*NPG;
        lsrc_s[tid] = s;
        ltr_s[tid] = clampT(etr[e]);
        ltp_s[tid] = clampT(etp[e]);
        int slot = atomicAdd(&lcnt[d], 1);
        if (slot < 2) llist[d][slot] = tid;
    }
    __syncthreads();

    const f32x4 zero = {0.f, 0.f, 0.f, 0.f};

    for (int l = 0; l < NLAYER; l++) {
        const unsigned short* baseH = encPh + (size_t)(l*6)*16384;
        const unsigned short* baseL = encPl + (size_t)(l*6)*16384;
        float accv[8];

        // ---- 1a: A = h@Wg0 -> M0, B = h@Wg1 + bg -> M1  (direct short frags)
        {
            int mat = w >> 1, ctbase = (w & 1) * 4;
            f32x4 acc[4] = {zero, zero, zero, zero};
            mm_nt_s16<4>(h_hi, h_lo, baseH + (size_t)mat*16384, baseL + (size_t)mat*16384,
                         ctbase, lane, acc);
            float* dst = mat ? M1 : M0;
            #pragma unroll
            for (int i = 0; i < 4; i++) {
                int n = (ctbase+i)*16 + (lane & 15);
                float bias = mat ? bg[l*HID + n] : 0.f;
                #pragma unroll
                for (int r = 0; r < 4; r++) {
                    int m = (lane >> 4)*4 + r;
                    dst[MC(m, n)] = acc[i][r] + bias;
                }
            }
        }
        __syncthreads();

        // ---- 2a: global-edge messages (s outer); accv held across 1b
        //      (R16 proved this is free)
        {
            float wgd = Wg[(size_t)l*257*HID + 256*HID + c];
            float base[8];
            unsigned mk[8];
            #pragma unroll
            for (int dd = 0; dd < 8; dd++) {
                base[dd] = M1[MC(dh2*8 + dd, c)];
                mk[dd]   = msk[dh2*8 + dd];
                accv[dd] = 0.f;
            }
            #pragma unroll
            for (int s = 0; s < NPG; s++) {
                float a = M0[MC(s, c)];
                #pragma unroll
                for (int dd = 0; dd < 8; dd++) {
                    if (mk[dd] & (1u << s)) {
                        float x = a + fmaf(d2m[dh2*8 + dd][s], wgd, base[dd]);
                        accv[dd] += silu_f(x);
                    }
                }
            }
        }
        __syncthreads();

        // ---- 1b: Al = h@Wl0 -> M0, Bl = h@Wl1 -> M1  (direct short frags)
        {
            int mat = w >> 1, ctbase = (w & 1) * 4;
            f32x4 acc[4] = {zero, zero, zero, zero};
            mm_nt_s16<4>(h_hi, h_lo, baseH + (size_t)(2+mat)*16384, baseL + (size_t)(2+mat)*16384,
                         ctbase, lane, acc);
            float* dst = mat ? M1 : M0;
            #pragma unroll
            for (int i = 0; i < 4; i++) {
                int n = (ctbase+i)*16 + (lane & 15);
                #pragma unroll
                for (int r = 0; r < 4; r++) {
                    int m = (lane >> 4)*4 + r;
                    dst[MC(m, n)] = acc[i][r];
                }
            }
        }
        __syncthreads();

        // ---- 2b: local-edge messages; write agg hi/lo shadows
        {
            const float* bA = bondA + (size_t)l*TMAX*HID;
            const float* bB = bondB + (size_t)l*TMAX*HID;
            #pragma unroll
            for (int dd = 0; dd < 8; dd++) {
                int d = dh2*8 + dd;
                float blb = M1[MC(d, c)];
                int lc2 = lcnt[d] < 2 ? lcnt[d] : 2;
                for (int i2 = 0; i2 < lc2; i2++) {
                    int ke = llist[d][i2];
                    float x = M0[MC(lsrc_s[ke], c)] + blb
                            + bA[ltr_s[ke]*HID + c] + bB[ltp_s[ke]*HID + c];
                    accv[dd] += silu_f(x);
                }
                unsigned short hi, lo;
                split2(accv[dd], hi, lo);
                int s = MC(d, c);
                g_hi[s] = (short)hi;
                g_lo[s] = (short)lo;
            }
        }
        __syncthreads();

        // ---- phase 3: U = h@Wn0 + agg@Wn1 + bn; h += silu(U)
        {
            f32x4 acc[2] = {zero, zero};
            mm_nt_s16<2>(h_hi, h_lo, baseH + (size_t)4*16384, baseL + (size_t)4*16384,
                         w*2, lane, acc);
            mm_nt_s16<2>(g_hi, g_lo, baseH + (size_t)5*16384, baseL + (size_t)5*16384,
                         w*2, lane, acc);
            __syncthreads();   // all waves' frag reads done before h update
            #pragma unroll
            for (int i = 0; i < 2; i++) {
                int n = (w*2+i)*16 + (lane & 15);
                float bnv = bn[l*HID + n];
                #pragma unroll
                for (int r = 0; r < 4; r++) {
                    int m = (lane >> 4)*4 + r;
                    int s = MC(m, n);
                    float old = bf16_to_f(h_hi[s]) + bf16_to_f(h_lo[s]);
                    float nv = old + silu_f(acc[i][r] + bnv);
                    unsigned short hi, lo;
                    split2(nv, hi, lo);
                    h_hi[s] = (short)hi;
                    h_lo[s] = (short)lo;
                }
            }
        }
        __syncthreads();
    }

    for (int idx = tid; idx < NPG*HID; idx += 256) {
        int n = idx >> 7, cc = idx & 127;
        int s = MC(n, cc);
        h[(size_t)g*NPG*HID + idx] = bf16_to_f(h_hi[s]) + bf16_to_f(h_lo[s]);
    }
}

// Edge MLP, MFMA path: x0=relu(prod@W00+pairT); x1=relu(x0@W1+b1); out=x1@W2+b2
__global__ void __launch_bounds__(256) k_mlp(
    const float* __restrict__ h,
    const int* __restrict__ eig, const int* __restrict__ egr, const int* __restrict__ egp,
    const float* __restrict__ pairT,
    const unsigned short* __restrict__ w0Ph, const unsigned short* __restrict__ w0Pl,
    const unsigned short* __restrict__ w1Ph, const unsigned short* __restrict__ w1Pl,
    const float* __restrict__ b1, const float* __restrict__ W2,
    const float* __restrict__ b2, float* __restrict__ out)
{
    __shared__ __align__(16) float h_s[NPG*HID];
    __shared__ __align__(16) short p_hi[NPG*HID], p_lo[NPG*HID];
    __shared__ __align__(16) short x_hi[NPG*HID], x_lo[NPG*HID];
    __shared__ int sgl[EG_PER_G], dgl[EG_PER_G], pidx[EG_PER_G];
    __shared__ float ypart[64];

    const int g = blockIdx.x;
    const int tid = threadIdx.x;
    const int lane = tid & 63;
    const int w = tid >> 6;

    for (int idx = tid; idx < NPG*HID; idx += 256)
        h_s[idx] = h[(size_t)g*NPG*HID + idx];
    if (tid < EG_PER_G) {
        int e = g*EG_PER_G + tid;
        sgl[tid] = eig[e] - g*NPG;
        dgl[tid] = eig[EG_TOT + e] - g*NPG;
        pidx[tid] = clampT(egr[e])*TMAX + clampT(egp[e]);
    }
    __syncthreads();
    const float b2v = b2[0];

    for (int e0 = 0; e0 < EG_PER_G; e0 += 16) {
        // ---- prod = h[s]*h[d], split to bf16 hi/lo (swizzled)
        {
            int m = tid >> 4, c0 = (tid & 15) * 8;
            int e = e0 + m;
            const float* ps = h_s + sgl[e]*HID + c0;
            const float* pd = h_s + dgl[e]*HID + c0;
            float4 s0 = *(const float4*)ps, s1 = *(const float4*)(ps + 4);
            float4 d0 = *(const float4*)pd, d1 = *(const float4*)(pd + 4);
            float vv[8] = {s0.x*d0.x, s0.y*d0.y, s0.z*d0.z, s0.w*d0.w,
                           s1.x*d1.x, s1.y*d1.y, s1.z*d1.z, s1.w*d1.w};
            bf16x8 H8, L8;
            split8(vv, H8, L8);
            int sidx = (m*HID + c0) ^ ((m & 7) << 3);
            *(bf16x8*)&p_hi[sidx] = H8;
            *(bf16x8*)&p_lo[sidx] = L8;
        }
        __syncthreads();

        // ---- x0 = relu(prod@W00 + pairT), split to bf16 (wave w: ct 2w,2w+1)
        {
            #pragma unroll
            for (int i = 0; i < 2; i++) {
                int ct = w*2 + i;
                f32x4 acc = {0.f, 0.f, 0.f, 0.f};
                acc = mm_ct_s16(p_hi, p_lo, w0Ph, w0Pl, ct, lane, acc);
                int n = ct*16 + (lane & 15);
                #pragma unroll
                for (int r = 0; r < 4; r++) {
                    int m = (lane >> 4)*4 + r;
                    float x0v = acc[r] + pairT[(size_t)pidx[e0 + m]*HID + n];
                    x0v = fmaxf(x0v, 0.f);
                    unsigned short hi, lo;
                    split2(x0v, hi, lo);
                    int sidx = (m*HID + n) ^ ((m & 7) << 3);
                    x_hi[sidx] = (short)hi;
                    x_lo[sidx] = (short)lo;
                }
            }
        }
        __syncthreads();

        // ---- x1 = relu(x0@W1 + b1); y = x1@W2 (wave w: cols 16w..16w+15)
        {
            f32x4 acc = {0.f, 0.f, 0.f, 0.f};
            acc = mm_ct_s16(x_hi, x_lo, w1Ph, w1Pl, w, lane, acc);
            int n = w*16 + (lane & 15);
            float b1v = b1[n], w2v = W2[n];
            float y[4];
            #pragma unroll
            for (int r = 0; r < 4; r++)
                y[r] = fmaxf(acc[r] + b1v, 0.f) * w2v;
            #pragma unroll
            for (int off = 1; off < 16; off <<= 1) {
                #pragma unroll
                for (int r = 0; r < 4; r++)
                    y[r] += __shfl_xor(y[r], off, 64);
            }
            if ((lane & 15) == 0) {
                #pragma unroll
                for (int r = 0; r < 4; r++)
                    ypart[w*16 + (lane >> 4)*4 + r] = y[r];
            }
        }
        __syncthreads();
        if (tid < 16)
            out[(size_t)g*EG_PER_G + e0 + tid] =
                ypart[tid] + ypart[16 + tid] + ypart[32 + tid] + ypart[48 + tid] + b2v;
        __syncthreads();
    }
}

extern "C" void kernel_launch(void* const* d_in, const int* in_sizes, int n_in,
                              void* d_out, int out_size, void* d_ws, size_t ws_size,
                              hipStream_t stream) {
    const int*   atom_type = (const int*)  d_in[0];
    const float* r_feat    = (const float*)d_in[1];
    const float* p_feat    = (const float*)d_in[2];
    const float* pos       = (const float*)d_in[3];
    const int*   eil       = (const int*)  d_in[4];
    const int*   etr       = (const int*)  d_in[5];
    const int*   etp       = (const int*)  d_in[6];
    const int*   eig       = (const int*)  d_in[7];
    const int*   egr       = (const int*)  d_in[8];
    const int*   egp       = (const int*)  d_in[9];
    const float* bond_emb  = (const float*)d_in[10];
    const float* atom_emb  = (const float*)d_in[11];
    const float* afW       = (const float*)d_in[12];
    const float* Wl        = (const float*)d_in[13];
    const float* bl        = (const float*)d_in[14];
    const float* Wg        = (const float*)d_in[15];
    const float* bg        = (const float*)d_in[16];
    const float* Wn        = (const float*)d_in[17];
    const float* bn        = (const float*)d_in[18];
    const float* W0        = (const float*)d_in[19];
    const float* b0        = (const float*)d_in[20];
    const float* W1        = (const float*)d_in[21];
    const float* b1        = (const float*)d_in[22];
    const float* W2        = (const float*)d_in[23];
    const float* b2        = (const float*)d_in[24];

    // workspace layout (~19.6 MB)
    float* h     = (float*)d_ws;                       // 32000*128
    float* bondA = h + (size_t)NNODES*HID;             // 6*32*128
    float* bondB = bondA + (size_t)NLAYER*TMAX*HID;
    float* pairT = bondB + (size_t)NLAYER*TMAX*HID;    // 32*32*128
    unsigned short* encPh = (unsigned short*)(pairT + (size_t)TMAX*TMAX*HID); // 36*16384
    unsigned short* encPl = encPh + (size_t)36*16384;
    unsigned short* w0Ph  = encPl + (size_t)36*16384;  // 16384
    unsigned short* w0Pl  = w0Ph + 16384;
    unsigned short* w1Ph  = w0Pl + 16384;              // 8192
    unsigned short* w1Pl  = w1Ph + 8192;
    float* out   = (float*)d_out;

    k_pack    <<<dim3(38),          dim3(256), 0, stream>>>(Wg, Wl, Wn, W0, W1,
                                                            encPh, encPl, w0Ph, w0Pl, w1Ph, w1Pl);
    k_tab_bond<<<dim3(NLAYER*TMAX), dim3(HID), 0, stream>>>(bond_emb, Wl, bl, bondA, bondB);
    k_tab_pair<<<dim3(TMAX*TMAX),   dim3(HID), 0, stream>>>(bond_emb, W0, b0, pairT);
    k_init_h  <<<dim3(NNODES/4),    dim3(256), 0, stream>>>(atom_type, r_feat, p_feat, atom_emb, afW, h);
    k_encoder <<<dim3(G_GRAPHS),    dim3(256), 0, stream>>>(pos, eil, etr, etp, eig,
                                                            Wg, bg, bn, bondA, bondB,
                                                            encPh, encPl, h);
    k_mlp     <<<dim3(G_GRAPHS),    dim3(256), 0, stream>>>(h, eig, egr, egp, pairT,
                                                            w0Ph, w0Pl, w1Ph, w1Pl,
                                                            b1, W2, b2, out);
}

// Round 18
// 531.422 us; speedup vs baseline: 1.1311x; 1.1311x over previous
//
#include <hip/hip_runtime.h>

// Mixed2DEpsNetwork: G=2000 graphs x 16 nodes, H=128, 6 EGNN layers + edge MLP.
// R18 = R16 (best stable: 557us) + dd-outer message phase: per-dest scalar
// state (~4 live regs) instead of base[8]/mk[8]/accv[8] (24 regs) -- the last
// candidate source of the ~10 dword/thread scratch under (256,4)'s forced
// 64-arch partition. M0 re-read per (dd,s) as stride-1 ds_read_b32 (~10us
// device-wide, cheap). Same summation order -> bitwise-identical results.
// (R17's short-shadow design REGRESSED: scratch 36->74MB; reverted.)
// bf16x3 MFMA, incremental-pointer kt-outer mm, cvt_pk splits, (256,4).

#define G_GRAPHS 2000
#define NPG 16
#define HID 128
#define FDIM 28
#define NLAYER 6
#define NNODES 32000
#define EL_PER_G 32
#define EG_PER_G 240
#define EL_TOT (G_GRAPHS*EL_PER_G)
#define EG_TOT (G_GRAPHS*EG_PER_G)
#define TMAX 32

// fp32 LDS [16][128] with per-row XOR swizzle (8-float granule)
#define MC(r_, c_) ((r_)*HID + ((c_) ^ (((r_) & 7) << 3)))

typedef __attribute__((ext_vector_type(8))) short bf16x8;
typedef __attribute__((ext_vector_type(4))) float f32x4;

__device__ __forceinline__ float silu_f(float x) {
    return x * __builtin_amdgcn_rcpf(1.0f + __expf(-x));
}
__device__ __forceinline__ int clampT(int t) {
    return t < 0 ? 0 : (t > TMAX-1 ? TMAX-1 : t);
}
__device__ __forceinline__ unsigned short bf16_rne(float x) {
    unsigned u = __float_as_uint(x);
    return (unsigned short)((u + 0x7FFFu + ((u >> 16) & 1u)) >> 16);
}
__device__ __forceinline__ void split2(float x, unsigned short &hi, unsigned short &lo) {
    hi = bf16_rne(x);
    float fh = __uint_as_float((unsigned)hi << 16);
    lo = bf16_rne(x - fh);
}

// pack 2 fp32 -> 2 bf16 (RNE) in one instruction
__device__ __forceinline__ unsigned cvtpk(float a, float b) {
    unsigned r;
    asm("v_cvt_pk_bf16_f32 %0, %1, %2" : "=v"(r) : "v"(a), "v"(b));
    return r;
}

// split 8 fp32 -> bf16 hi/lo fragments (in registers), via cvt_pk
__device__ __forceinline__ void split8(const float* vv, bf16x8& h8, bf16x8& l8) {
    union { unsigned u[4]; bf16x8 v; } H, L;
    #pragma unroll
    for (int i = 0; i < 4; i++) {
        unsigned hp = cvtpk(vv[2*i], vv[2*i+1]);
        float fh0 = __uint_as_float(hp << 16);
        float fh1 = __uint_as_float(hp & 0xffff0000u);
        H.u[i] = hp;
        L.u[i] = cvtpk(vv[2*i] - fh0, vv[2*i+1] - fh1);
    }
    h8 = H.v; l8 = L.v;
}

// kt-outer GEMM over K=128, NT contiguous ct-tiles, from a swizzled fp32
// [16][128] LDS buffer. Incremental B pointers + unroll 1 on kt: only one
// pointer-pair per stream stays live. Per-acc chain order: kt asc; hh,hl,lh.
template<int NT>
__device__ __forceinline__ void mm_nt_f32(const float* __restrict__ abuf,
                                          const unsigned short* __restrict__ Bh,
                                          const unsigned short* __restrict__ Bl,
                                          int ctbase, int lane, f32x4* acc) {
    const int n = lane & 15, kq = lane >> 4;
    const int sw = (n & 7) << 3;
    const float* ap = abuf + n*HID;
    const unsigned short* bh = Bh + ((size_t)(ctbase*4)*64 + lane)*8;
    const unsigned short* bl = Bl + ((size_t)(ctbase*4)*64 + lane)*8;
    #pragma unroll 1
    for (int kt = 0; kt < 4; kt++) {
        int idx = (kt*32 + kq*8) ^ sw;
        float4 v0 = *(const float4*)(ap + idx);
        float4 v1 = *(const float4*)(ap + idx + 4);
        float vv[8] = {v0.x, v0.y, v0.z, v0.w, v1.x, v1.y, v1.z, v1.w};
        bf16x8 ah, al;
        split8(vv, ah, al);
        const unsigned short* ph = bh;
        const unsigned short* pl = bl;
        #pragma unroll
        for (int t = 0; t < NT; t++) {
            bf16x8 vh = *(const bf16x8*)ph;
            bf16x8 vl = *(const bf16x8*)pl;
            acc[t] = __builtin_amdgcn_mfma_f32_16x16x32_bf16(ah, vh, acc[t], 0, 0, 0);
            acc[t] = __builtin_amdgcn_mfma_f32_16x16x32_bf16(ah, vl, acc[t], 0, 0, 0);
            acc[t] = __builtin_amdgcn_mfma_f32_16x16x32_bf16(al, vh, acc[t], 0, 0, 0);
            ph += 2048;   // next ct-tile (4 kt * 64 lanes * 8)
            pl += 2048;
        }
        bh += 512;        // next kt (64 lanes * 8)
        bl += 512;
    }
}

// One 16x16 tile, A from bf16-short swizzled buffer (MLP path), incremental ptrs.
__device__ __forceinline__ f32x4 mm_ct_s16(const short* __restrict__ ahbuf,
                                           const short* __restrict__ albuf,
                                           const unsigned short* __restrict__ Bh,
                                           const unsigned short* __restrict__ Bl,
                                           int ct, int lane, f32x4 acc) {
    const int n = lane & 15, kq = lane >> 4;
    const unsigned short* bh = Bh + ((size_t)(ct*4)*64 + lane)*8;
    const unsigned short* bl = Bl + ((size_t)(ct*4)*64 + lane)*8;
    #pragma unroll 1
    for (int kt = 0; kt < 4; kt++) {
        int sidx = (n*HID + kt*32 + kq*8) ^ ((n & 7) << 3);
        bf16x8 ah = *(const bf16x8*)(ahbuf + sidx);
        bf16x8 al = *(const bf16x8*)(albuf + sidx);
        bf16x8 vh = *(const bf16x8*)bh;
        bf16x8 vl = *(const bf16x8*)bl;
        acc = __builtin_amdgcn_mfma_f32_16x16x32_bf16(ah, vh, acc, 0, 0, 0);
        acc = __builtin_amdgcn_mfma_f32_16x16x32_bf16(ah, vl, acc, 0, 0, 0);
        acc = __builtin_amdgcn_mfma_f32_16x16x32_bf16(al, vh, acc, 0, 0, 0);
        bh += 512;
        bl += 512;
    }
    return acc;
}

// Pack weights into MFMA B-fragment order, bf16 hi/lo.
// blocks 0..35: encoder (layer l = b/6, mat m = b%6: Wg0,Wg1,Wl0,Wl1,Wn0,Wn1)
// block 36: W00 (W0 rows 0..127); block 37: W1 (128x64).
__global__ void __launch_bounds__(256) k_pack(
    const float* __restrict__ Wg, const float* __restrict__ Wl,
    const float* __restrict__ Wn, const float* __restrict__ W0,
    const float* __restrict__ W1,
    unsigned short* __restrict__ encPh, unsigned short* __restrict__ encPl,
    unsigned short* __restrict__ w0Ph, unsigned short* __restrict__ w0Pl,
    unsigned short* __restrict__ w1Ph, unsigned short* __restrict__ w1Pl)
{
    int b = blockIdx.x, t = threadIdx.x;
    const float* src; int ldN, elems; unsigned short *dh, *dl;
    if (b < 36) {
        int l = b / 6, m = b % 6;
        src = (m == 0) ? Wg + (size_t)l*257*HID
            : (m == 1) ? Wg + (size_t)l*257*HID + 128*HID
            : (m == 2) ? Wl + (size_t)l*512*HID
            : (m == 3) ? Wl + (size_t)l*512*HID + 128*HID
            : (m == 4) ? Wn + (size_t)l*256*HID
            :            Wn + (size_t)l*256*HID + 128*HID;
        ldN = HID; elems = 16384;
        dh = encPh + (size_t)b*16384; dl = encPl + (size_t)b*16384;
    } else if (b == 36) {
        src = W0; ldN = HID; elems = 16384; dh = w0Ph; dl = w0Pl;
    } else {
        src = W1; ldN = 64; elems = 8192; dh = w1Ph; dl = w1Pl;
    }
    for (int idx = t; idx < elems; idx += 256) {
        int j = idx & 7, lane = (idx >> 3) & 63, kt = (idx >> 9) & 3, ct = idx >> 11;
        int k = kt*32 + (lane >> 4)*8 + j;
        int n = ct*16 + (lane & 15);
        unsigned short hi, lo;
        split2(src[(size_t)k*ldN + n], hi, lo);
        dh[idx] = hi; dl[idx] = lo;
    }
}

// bondA[l][t][c] = bond_emb[t] @ Wl[l,256:384] + bl[l];  bondB: rows 384:512.
__global__ void __launch_bounds__(HID) k_tab_bond(
    const float* __restrict__ bond_emb, const float* __restrict__ Wl,
    const float* __restrict__ bl, float* __restrict__ bondA, float* __restrict__ bondB)
{
    int l = blockIdx.x >> 5, t = blockIdx.x & 31, c = threadIdx.x;
    const float* WlL = Wl + (size_t)l*512*HID;
    float accA = bl[l*HID + c], accB = 0.f;
    #pragma unroll 4
    for (int k = 0; k < HID; k++) {
        float e = bond_emb[t*HID + k];
        accA = fmaf(e, WlL[(256+k)*HID + c], accA);
        accB = fmaf(e, WlL[(384+k)*HID + c], accB);
    }
    bondA[(l*TMAX + t)*HID + c] = accA;
    bondB[(l*TMAX + t)*HID + c] = accB;
}

// pairT[tr][tp][c] = (bond_emb[tr]*bond_emb[tp]) @ W0[128:256] + b0
__global__ void __launch_bounds__(HID) k_tab_pair(
    const float* __restrict__ bond_emb, const float* __restrict__ W0,
    const float* __restrict__ b0, float* __restrict__ pairT)
{
    int tr = blockIdx.x >> 5, tp = blockIdx.x & 31, c = threadIdx.x;
    float acc = b0[c];
    #pragma unroll 4
    for (int k = 0; k < HID; k++)
        acc = fmaf(bond_emb[tr*HID + k] * bond_emb[tp*HID + k], W0[(HID+k)*HID + c], acc);
    pairT[(size_t)blockIdx.x*HID + c] = acc;
}

// h[n] = concat(atom_emb[at] + r@W, (p-r)@W)
__global__ void __launch_bounds__(256) k_init_h(
    const int* __restrict__ atom_type, const float* __restrict__ r_feat,
    const float* __restrict__ p_feat, const float* __restrict__ atom_emb,
    const float* __restrict__ afW, float* __restrict__ h)
{
    int n = blockIdx.x*4 + (threadIdx.x >> 6);
    int j = threadIdx.x & 63;
    int at = atom_type[n];
    float accr = 0.f, accp = 0.f;
    #pragma unroll
    for (int k = 0; k < FDIM; k++) {
        float w = afW[k*64 + j];
        accr = fmaf(r_feat[n*FDIM + k], w, accr);
        accp = fmaf(p_feat[n*FDIM + k], w, accp);
    }
    h[n*HID + j]      = atom_emb[at*64 + j] + accr;
    h[n*HID + 64 + j] = accp - accr;
}

// One block per graph; all 6 layers fused. LDS ~34.8KB (4 blocks/CU), (256,4).
__global__ void __launch_bounds__(256, 4) k_encoder(
    const float* __restrict__ pos,
    const int* __restrict__ eil, const int* __restrict__ etr, const int* __restrict__ etp,
    const int* __restrict__ eig,
    const float* __restrict__ Wg, const float* __restrict__ bg,
    const float* __restrict__ bn,
    const float* __restrict__ bondA, const float* __restrict__ bondB,
    const unsigned short* __restrict__ encPh, const unsigned short* __restrict__ encPl,
    float* __restrict__ h)
{
    __shared__ __align__(16) float h_f[NPG*HID];            // fp32 h (swizzled)
    __shared__ __align__(16) float M0[NPG*HID], M1[NPG*HID];// A/Al, B/Bl (swizzled)
    __shared__ __align__(16) float M2[NPG*HID];             // partial/final agg
    __shared__ float d2m[NPG][NPG];
    __shared__ unsigned msk[NPG];
    __shared__ float px[NPG], py[NPG], pz[NPG];
    __shared__ int llist[NPG][2];
    __shared__ int lcnt[NPG];
    __shared__ int lsrc_s[EL_PER_G], ltr_s[EL_PER_G], ltp_s[EL_PER_G];

    const int g = blockIdx.x;
    const int tid = threadIdx.x;
    const int lane = tid & 63;
    const int w    = tid >> 6;     // wave id 0..3
    const int c    = tid & 127;    // phase-2 column
    const int dh2  = tid >> 7;     // phase-2 dest half

    // ---- load h (swizzled) + topology
    for (int idx = tid; idx < NPG*HID; idx += 256) {
        int n = idx >> 7, cc = idx & 127;
        h_f[MC(n, cc)] = h[(size_t)g*NPG*HID + idx];
    }
    if (tid < NPG) {
        px[tid] = pos[(g*NPG + tid)*3 + 0];
        py[tid] = pos[(g*NPG + tid)*3 + 1];
        pz[tid] = pos[(g*NPG + tid)*3 + 2];
        lcnt[tid] = 0; msk[tid] = 0u;
    }
    __syncthreads();
    if (tid < EG_PER_G) {
        int e = g*EG_PER_G + tid;
        int s = eig[e] - g*NPG;
        int d = eig[EG_TOT + e] - g*NPG;
        float dx = px[s]-px[d], dy = py[s]-py[d], dz = pz[s]-pz[d];
        d2m[d][s] = dx*dx + dy*dy + dz*dz;
        atomicOr(&msk[d], 1u << s);
    }
    if (tid < EL_PER_G) {
        int e = g*EL_PER_G + tid;
        int s = eil[e] - g*NPG;
        int d = eil[EL_TOT + e] - g*NPG;
        lsrc_s[tid] = s;
        ltr_s[tid] = clampT(etr[e]);
        ltp_s[tid] = clampT(etp[e]);
        int slot = atomicAdd(&lcnt[d], 1);
        if (slot < 2) llist[d][slot] = tid;
    }
    __syncthreads();

    const f32x4 zero = {0.f, 0.f, 0.f, 0.f};

    for (int l = 0; l < NLAYER; l++) {
        const unsigned short* baseH = encPh + (size_t)(l*6)*16384;
        const unsigned short* baseL = encPl + (size_t)(l*6)*16384;

        // ---- 1a: A = h@Wg0 -> M0, B = h@Wg1 + bg -> M1  (kt-outer, NT=4)
        {
            int mat = w >> 1, ctbase = (w & 1) * 4;
            f32x4 acc[4] = {zero, zero, zero, zero};
            mm_nt_f32<4>(h_f, baseH + (size_t)mat*16384, baseL + (size_t)mat*16384,
                         ctbase, lane, acc);
            float* dst = mat ? M1 : M0;
            #pragma unroll
            for (int i = 0; i < 4; i++) {
                int n = (ctbase+i)*16 + (lane & 15);
                float bias = mat ? bg[l*HID + n] : 0.f;
                #pragma unroll
                for (int r = 0; r < 4; r++) {
                    int m = (lane >> 4)*4 + r;
                    dst[MC(m, n)] = acc[i][r] + bias;
                }
            }
        }
        __syncthreads();

        // ---- 2a: global-edge messages, dd-outer (scalar per-dd state);
        //      partial agg staged to M2 (no regs cross the 1b GEMM)
        {
            float wgd = Wg[(size_t)l*257*HID + 256*HID + c];
            #pragma unroll 1
            for (int dd = 0; dd < 8; dd++) {
                int d = dh2*8 + dd;
                float base = M1[MC(d, c)];
                unsigned m = msk[d];
                float acc = 0.f;
                #pragma unroll
                for (int s = 0; s < NPG; s++) {
                    if (m & (1u << s)) {
                        float x = M0[MC(s, c)] + fmaf(d2m[d][s], wgd, base);
                        acc += silu_f(x);
                    }
                }
                M2[MC(d, c)] = acc;
            }
        }
        __syncthreads();

        // ---- 1b: Al = h@Wl0 -> M0, Bl = h@Wl1 -> M1  (kt-outer, NT=4)
        {
            int mat = w >> 1, ctbase = (w & 1) * 4;
            f32x4 acc[4] = {zero, zero, zero, zero};
            mm_nt_f32<4>(h_f, baseH + (size_t)(2+mat)*16384, baseL + (size_t)(2+mat)*16384,
                         ctbase, lane, acc);
            float* dst = mat ? M1 : M0;
            #pragma unroll
            for (int i = 0; i < 4; i++) {
                int n = (ctbase+i)*16 + (lane & 15);
                #pragma unroll
                for (int r = 0; r < 4; r++) {
                    int m = (lane >> 4)*4 + r;
                    dst[MC(m, n)] = acc[i][r];
                }
            }
        }
        __syncthreads();

        // ---- 2b: local-edge messages, dd-outer; M2 += local terms (same order)
        {
            const float* bA = bondA + (size_t)l*TMAX*HID;
            const float* bB = bondB + (size_t)l*TMAX*HID;
            #pragma unroll 1
            for (int dd = 0; dd < 8; dd++) {
                int d = dh2*8 + dd;
                float acc = M2[MC(d, c)];           // partial agg back
                float blb = M1[MC(d, c)];
                int lc2 = lcnt[d] < 2 ? lcnt[d] : 2;
                for (int i2 = 0; i2 < lc2; i2++) {
                    int ke = llist[d][i2];
                    float x = M0[MC(lsrc_s[ke], c)] + blb
                            + bA[ltr_s[ke]*HID + c] + bB[ltp_s[ke]*HID + c];
                    acc += silu_f(x);
                }
                M2[MC(d, c)] = acc;                 // final agg (own (d,c): safe)
            }
        }
        __syncthreads();

        // ---- phase 3: U = h@Wn0 + agg@Wn1 + bn; h += silu(U)  (kt-outer, NT=2 x2)
        {
            f32x4 acc[2] = {zero, zero};
            mm_nt_f32<2>(h_f, baseH + (size_t)4*16384, baseL + (size_t)4*16384,
                         w*2, lane, acc);
            mm_nt_f32<2>(M2,  baseH + (size_t)5*16384, baseL + (size_t)5*16384,
                         w*2, lane, acc);
            __syncthreads();   // all waves' h_f/M2 A-frag reads done before
                               // any wave writes its h_f columns (race fix)
            #pragma unroll
            for (int i = 0; i < 2; i++) {
                int n = (w*2+i)*16 + (lane & 15);
                float bnv = bn[l*HID + n];
                #pragma unroll
                for (int r = 0; r < 4; r++) {
                    int m = (lane >> 4)*4 + r;
                    h_f[MC(m, n)] += silu_f(acc[i][r] + bnv);
                }
            }
        }
        __syncthreads();
    }

    for (int idx = tid; idx < NPG*HID; idx += 256) {
        int n = idx >> 7, cc = idx & 127;
        h[(size_t)g*NPG*HID + idx] = h_f[MC(n, cc)];
    }
}

// Edge MLP, MFMA path: x0=relu(prod@W00+pairT); x1=relu(x0@W1+b1); out=x1@W2+b2
__global__ void __launch_bounds__(256) k_mlp(
    const float* __restrict__ h,
    const int* __restrict__ eig, const int* __restrict__ egr, const int* __restrict__ egp,
    const float* __restrict__ pairT,
    const unsigned short* __restrict__ w0Ph, const unsigned short* __restrict__ w0Pl,
    const unsigned short* __restrict__ w1Ph, const unsigned short* __restrict__ w1Pl,
    const float* __restrict__ b1, const float* __restrict__ W2,
    const float* __restrict__ b2, float* __restrict__ out)
{
    __shared__ __align__(16) float h_s[NPG*HID];
    __shared__ __align__(16) short p_hi[NPG*HID], p_lo[NPG*HID];
    __shared__ __align__(16) short x_hi[NPG*HID], x_lo[NPG*HID];
    __shared__ int sgl[EG_PER_G], dgl[EG_PER_G], pidx[EG_PER_G];
    __shared__ float ypart[64];

    const int g = blockIdx.x;
    const int tid = threadIdx.x;
    const int lane = tid & 63;
    const int w = tid >> 6;

    for (int idx = tid; idx < NPG*HID; idx += 256)
        h_s[idx] = h[(size_t)g*NPG*HID + idx];
    if (tid < EG_PER_G) {
        int e = g*EG_PER_G + tid;
        sgl[tid] = eig[e] - g*NPG;
        dgl[tid] = eig[EG_TOT + e] - g*NPG;
        pidx[tid] = clampT(egr[e])*TMAX + clampT(egp[e]);
    }
    __syncthreads();
    const float b2v = b2[0];

    for (int e0 = 0; e0 < EG_PER_G; e0 += 16) {
        // ---- prod = h[s]*h[d], split to bf16 hi/lo (swizzled)
        {
            int m = tid >> 4, c0 = (tid & 15) * 8;
            int e = e0 + m;
            const float* ps = h_s + sgl[e]*HID + c0;
            const float* pd = h_s + dgl[e]*HID + c0;
            float4 s0 = *(const float4*)ps, s1 = *(const float4*)(ps + 4);
            float4 d0 = *(const float4*)pd, d1 = *(const float4*)(pd + 4);
            float vv[8] = {s0.x*d0.x, s0.y*d0.y, s0.z*d0.z, s0.w*d0.w,
                           s1.x*d1.x, s1.y*d1.y, s1.z*d1.z, s1.w*d1.w};
            bf16x8 H8, L8;
            split8(vv, H8, L8);
            int sidx = (m*HID + c0) ^ ((m & 7) << 3);
            *(bf16x8*)&p_hi[sidx] = H8;
            *(bf16x8*)&p_lo[sidx] = L8;
        }
        __syncthreads();

        // ---- x0 = relu(prod@W00 + pairT), split to bf16 (wave w: ct 2w,2w+1)
        {
            #pragma unroll
            for (int i = 0; i < 2; i++) {
                int ct = w*2 + i;
                f32x4 acc = {0.f, 0.f, 0.f, 0.f};
                acc = mm_ct_s16(p_hi, p_lo, w0Ph, w0Pl, ct, lane, acc);
                int n = ct*16 + (lane & 15);
                #pragma unroll
                for (int r = 0; r < 4; r++) {
                    int m = (lane >> 4)*4 + r;
                    float x0v = acc[r] + pairT[(size_t)pidx[e0 + m]*HID + n];
                    x0v = fmaxf(x0v, 0.f);
                    unsigned short hi, lo;
                    split2(x0v, hi, lo);
                    int sidx = (m*HID + n) ^ ((m & 7) << 3);
                    x_hi[sidx] = (short)hi;
                    x_lo[sidx] = (short)lo;
                }
            }
        }
        __syncthreads();

        // ---- x1 = relu(x0@W1 + b1); y = x1@W2 (wave w: cols 16w..16w+15)
        {
            f32x4 acc = {0.f, 0.f, 0.f, 0.f};
            acc = mm_ct_s16(x_hi, x_lo, w1Ph, w1Pl, w, lane, acc);
            int n = w*16 + (lane & 15);
            float b1v = b1[n], w2v = W2[n];
            float y[4];
            #pragma unroll
            for (int r = 0; r < 4; r++)
                y[r] = fmaxf(acc[r] + b1v, 0.f) * w2v;
            #pragma unroll
            for (int off = 1; off < 16; off <<= 1) {
                #pragma unroll
                for (int r = 0; r < 4; r++)
                    y[r] += __shfl_xor(y[r], off, 64);
            }
            if ((lane & 15) == 0) {
                #pragma unroll
                for (int r = 0; r < 4; r++)
                    ypart[w*16 + (lane >> 4)*4 + r] = y[r];
            }
        }
        __syncthreads();
        if (tid < 16)
            out[(size_t)g*EG_PER_G + e0 + tid] =
                ypart[tid] + ypart[16 + tid] + ypart[32 + tid] + ypart[48 + tid] + b2v;
        __syncthreads();
    }
}

extern "C" void kernel_launch(void* const* d_in, const int* in_sizes, int n_in,
                              void* d_out, int out_size, void* d_ws, size_t ws_size,
                              hipStream_t stream) {
    const int*   atom_type = (const int*)  d_in[0];
    const float* r_feat    = (const float*)d_in[1];
    const float* p_feat    = (const float*)d_in[2];
    const float* pos       = (const float*)d_in[3];
    const int*   eil       = (const int*)  d_in[4];
    const int*   etr       = (const int*)  d_in[5];
    const int*   etp       = (const int*)  d_in[6];
    const int*   eig       = (const int*)  d_in[7];
    const int*   egr       = (const int*)  d_in[8];
    const int*   egp       = (const int*)  d_in[9];
    const float* bond_emb  = (const float*)d_in[10];
    const float* atom_emb  = (const float*)d_in[11];
    const float* afW       = (const float*)d_in[12];
    const float* Wl        = (const float*)d_in[13];
    const float* bl        = (const float*)d_in[14];
    const float* Wg        = (const float*)d_in[15];
    const float* bg        = (const float*)d_in[16];
    const float* Wn        = (const float*)d_in[17];
    const float* bn        = (const float*)d_in[18];
    const float* W0        = (const float*)d_in[19];
    const float* b0        = (const float*)d_in[20];
    const float* W1        = (const float*)d_in[21];
    const float* b1        = (const float*)d_in[22];
    const float* W2        = (const float*)d_in[23];
    const float* b2        = (const float*)d_in[24];

    // workspace layout (~19.6 MB)
    float* h     = (float*)d_ws;                       // 32000*128
    float* bondA = h + (size_t)NNODES*HID;             // 6*32*128
    float* bondB = bondA + (size_t)NLAYER*TMAX*HID;
    float* pairT = bondB + (size_t)NLAYER*TMAX*HID;    // 32*32*128
    unsigned short* encPh = (unsigned short*)(pairT + (size_t)TMAX*TMAX*HID); // 36*16384
    unsigned short* encPl = encPh + (size_t)36*16384;
    unsigned short* w0Ph  = encPl + (size_t)36*16384;  // 16384
    unsigned short* w0Pl  = w0Ph + 16384;
    unsigned short* w1Ph  = w0Pl + 16384;              // 8192
    unsigned short* w1Pl  = w1Ph + 8192;
    float* out   = (float*)d_out;

    k_pack    <<<dim3(38),          dim3(256), 0, stream>>>(Wg, Wl, Wn, W0, W1,
                                                            encPh, encPl, w0Ph, w0Pl, w1Ph, w1Pl);
    k_tab_bond<<<dim3(NLAYER*TMAX), dim3(HID), 0, stream>>>(bond_emb, Wl, bl, bondA, bondB);
    k_tab_pair<<<dim3(TMAX*TMAX),   dim3(HID), 0, stream>>>(bond_emb, W0, b0, pairT);
    k_init_h  <<<dim3(NNODES/4),    dim3(256), 0, stream>>>(atom_type, r_feat, p_feat, atom_emb, afW, h);
    k_encoder <<<dim3(G_GRAPHS),    dim3(256), 0, stream>>>(pos, eil, etr, etp, eig,
                                                            Wg, bg, bn, bondA, bondB,
                                                            encPh, encPl, h);
    k_mlp     <<<dim3(G_GRAPHS),    dim3(256), 0, stream>>>(h, eig, egr, egp, pairT,
                                                            w0Ph, w0Pl, w1Ph, w1Pl,
                                                            b1, W2, b2, out);
}